// Round 6
// baseline (46.762 us; speedup 1.0000x reference)
//
#include <hip/hip_runtime.h>
#include <hip/hip_bf16.h>

#define B_SZ 1024
#define F_SZ 2048
#define NK   32
#define NCOL 256            // NK*KD
#define OUTF 2080           // F + NK

typedef __attribute__((ext_vector_type(8))) short short8v;
typedef __attribute__((ext_vector_type(8))) unsigned short ushort8v;
typedef __attribute__((ext_vector_type(4))) float f32x4;

static __device__ __forceinline__ unsigned short f2bf(float v) {
  __hip_bfloat16 h = __float2bfloat16(v);   // RNE
  return reinterpret_cast<unsigned short&>(h);
}

// ---------------------------------------------------------------------------
// k0: role-split prep, 256 blocks x 256 thr.
//   blocks 0..127   : W[2048][256] f32 -> wt[256][2048] bf16 (LDS transpose)
//   blocks 128..255 : copy x rows into out[:, 0:2048]
// ---------------------------------------------------------------------------
__global__ __launch_bounds__(256) void k0_prep(
    const float* __restrict__ W, const float* __restrict__ x,
    unsigned short* __restrict__ wt, float* __restrict__ out) {
  int bid = blockIdx.x;
  int t = threadIdx.x;

  if (bid < 128) {
    __shared__ unsigned short tile[64][66];   // [k][n], pad
    int kt = bid & 31, ntile = bid >> 5;
    int k0 = kt * 64, n0 = ntile * 64;
    int r  = t >> 2;           // 0..63
    int c0 = (t & 3) * 16;
#pragma unroll
    for (int u = 0; u < 4; ++u) {
      float4 v = *reinterpret_cast<const float4*>(
          &W[(size_t)(k0 + r) * NCOL + n0 + c0 + 4 * u]);
      tile[r][c0 + 4 * u + 0] = f2bf(v.x);
      tile[r][c0 + 4 * u + 1] = f2bf(v.y);
      tile[r][c0 + 4 * u + 2] = f2bf(v.z);
      tile[r][c0 + 4 * u + 3] = f2bf(v.w);
    }
    __syncthreads();
    int n  = t >> 2;           // output row in wt
    int kq = (t & 3) * 16;
    ushort8v o0, o1;
#pragma unroll
    for (int u = 0; u < 8; ++u) o0[u] = tile[kq + u][n];
#pragma unroll
    for (int u = 0; u < 8; ++u) o1[u] = tile[kq + 8 + u][n];
    unsigned short* dst = &wt[(size_t)(n0 + n) * F_SZ + k0 + kq];
    *reinterpret_cast<ushort8v*>(dst)     = o0;
    *reinterpret_cast<ushort8v*>(dst + 8) = o1;
  } else {
    // copy: 128 blocks x 256 thr, 16 float4 each (524288 total)
    const float4* x4 = reinterpret_cast<const float4*>(x);
    int idx = (bid - 128) * 256 + t;
#pragma unroll
    for (int it = 0; it < 16; ++it, idx += 128 * 256) {
      int i  = idx >> 9;          // 512 float4 per x row
      int c4 = idx & 511;
      float4 v = x4[idx];
      *reinterpret_cast<float4*>(&out[(size_t)i * OUTF + c4 * 4]) = v;
    }
  }
}

// ---------------------------------------------------------------------------
// k1: barrier-free GEMM.  m[1024][256] = x . W, bf16 MFMA.
// 256 blocks x 512 thr; block = 32x32 tile (mt=bid&31: x-slice XCD-local).
// 8 waves split K (wave w owns [w*256, w*256+256)); direct global->reg loads:
// A = f32 x + inline cvt, B = contiguous bf16 from wt (2 x 16B per step).
// One __syncthreads total (LDS accumulator reduce).
// ---------------------------------------------------------------------------
__global__ __launch_bounds__(512) void k1_gemm(
    const float* __restrict__ x, const unsigned short* __restrict__ wt,
    float* __restrict__ m) {
  __shared__ float red[8][16][64];   // 32 KB

  int bid = blockIdx.x;
  int mt = bid & 31, nt = bid >> 5;
  int i0 = mt * 32, n0 = nt * 32;

  int t = threadIdx.x;
  int w = t >> 6, l = t & 63;
  int hi = l >> 4, r16 = l & 15;
  int hi8 = hi * 8;

  f32x4 acc[2][2];
#pragma unroll
  for (int mi = 0; mi < 2; ++mi)
#pragma unroll
    for (int ni = 0; ni < 2; ++ni) acc[mi][ni] = (f32x4)(0.f);

  for (int ks = 0; ks < 8; ++ks) {
    int kc = w * 256 + ks * 32;

    short8v af[2];
#pragma unroll
    for (int mi = 0; mi < 2; ++mi) {
      const float* ap = &x[(size_t)(i0 + mi * 16 + r16) * F_SZ + kc + hi8];
      float4 v0 = *reinterpret_cast<const float4*>(ap);
      float4 v1 = *reinterpret_cast<const float4*>(ap + 4);
      af[mi][0] = (short)f2bf(v0.x); af[mi][1] = (short)f2bf(v0.y);
      af[mi][2] = (short)f2bf(v0.z); af[mi][3] = (short)f2bf(v0.w);
      af[mi][4] = (short)f2bf(v1.x); af[mi][5] = (short)f2bf(v1.y);
      af[mi][6] = (short)f2bf(v1.z); af[mi][7] = (short)f2bf(v1.w);
    }

    short8v bfr[2];
#pragma unroll
    for (int ni = 0; ni < 2; ++ni)
      bfr[ni] = *reinterpret_cast<const short8v*>(
          &wt[(size_t)(n0 + ni * 16 + r16) * F_SZ + kc + hi8]);

#pragma unroll
    for (int mi = 0; mi < 2; ++mi)
#pragma unroll
      for (int ni = 0; ni < 2; ++ni)
        acc[mi][ni] = __builtin_amdgcn_mfma_f32_16x16x32_bf16(
            af[mi], bfr[ni], acc[mi][ni], 0, 0, 0);
  }

#pragma unroll
  for (int mi = 0; mi < 2; ++mi)
#pragma unroll
    for (int ni = 0; ni < 2; ++ni)
#pragma unroll
      for (int r = 0; r < 4; ++r)
        red[w][mi * 8 + ni * 4 + r][l] = acc[mi][ni][r];   // contig per wave: conflict-free
  __syncthreads();

#pragma unroll
  for (int s = 0; s < 2; ++s) {
    int slot = t + s * 512;            // 1024 slots = 16 regs x 64 lanes
    int reg = slot >> 6, lane = slot & 63;
    float v = 0.f;
#pragma unroll
    for (int ww = 0; ww < 8; ++ww) v += red[ww][reg][lane];
    int mi = reg >> 3, ni = (reg >> 2) & 1, r = reg & 3;
    int row = i0 + mi * 16 + (lane >> 4) * 4 + r;   // C/D: col=lane&15, row=(lane>>4)*4+reg
    int col = n0 + ni * 16 + (lane & 15);
    m[(size_t)row * NCOL + col] = v;
  }
}

// ---------------------------------------------------------------------------
// k2: pairwise L1+exp, 256 blocks x 1024 thr (16 waves = 4/SIMD).
// Block = 4 i-rows; thread (jc=t>>5 over 32 chunks x 32 j, k=t&31) keeps 4
// i-row fragments in registers (each 32B m[j] load serves 4 exps); LDS reduce;
// writes out[i][2048+k] directly.  m (1MB) is L2-resident.
// ---------------------------------------------------------------------------
__global__ __launch_bounds__(1024) void k2_pairwise(
    const float* __restrict__ m, float* __restrict__ out) {
  __shared__ float red[32][4][33];

  int bid = blockIdx.x;
  int t = threadIdx.x;
  int k  = t & 31;
  int jc = t >> 5;          // 0..31
  int i0 = bid * 4;
  int j0 = jc * 32;

  const float4* mv = reinterpret_cast<const float4*>(m);  // m[i][c]: idx = i*64 + c4
  float4 a0[4], a1[4];
#pragma unroll
  for (int r = 0; r < 4; ++r) {
    a0[r] = mv[(size_t)(i0 + r) * 64 + k * 2];
    a1[r] = mv[(size_t)(i0 + r) * 64 + k * 2 + 1];
  }

  float acc[4] = {0.f, 0.f, 0.f, 0.f};
#pragma unroll 2
  for (int jj = 0; jj < 32; ++jj) {
    int j = j0 + jj;
    float4 c0 = mv[(size_t)j * 64 + k * 2];
    float4 c1 = mv[(size_t)j * 64 + k * 2 + 1];
#pragma unroll
    for (int r = 0; r < 4; ++r) {
      float s = fabsf(a0[r].x - c0.x) + fabsf(a0[r].y - c0.y) +
                fabsf(a0[r].z - c0.z) + fabsf(a0[r].w - c0.w) +
                fabsf(a1[r].x - c1.x) + fabsf(a1[r].y - c1.y) +
                fabsf(a1[r].z - c1.z) + fabsf(a1[r].w - c1.w);
      acc[r] += __expf(-s);
    }
  }

#pragma unroll
  for (int r = 0; r < 4; ++r) red[jc][r][k] = acc[r];
  __syncthreads();

  if (t < 128) {
    int r = t >> 5, kk = t & 31;
    float s = 0.f;
#pragma unroll
    for (int c = 0; c < 32; ++c) s += red[c][r][kk];
    out[(size_t)(i0 + r) * OUTF + F_SZ + kk] = s;
  }
}

extern "C" void kernel_launch(void* const* d_in, const int* in_sizes, int n_in,
                              void* d_out, int out_size, void* d_ws, size_t ws_size,
                              hipStream_t stream) {
  const float* x = (const float*)d_in[0];
  const float* W = (const float*)d_in[1];
  float* out = (float*)d_out;
  char* ws = (char*)d_ws;

  const size_t MB = 1u << 20;
  unsigned short* wt = (unsigned short*)ws;   // 1 MB
  float* m = (float*)(ws + MB);               // 1 MB

  k0_prep<<<dim3(256), 256, 0, stream>>>(W, x, wt, out);
  k1_gemm<<<dim3(256), 512, 0, stream>>>(x, wt, m);
  k2_pairwise<<<dim3(256), 1024, 0, stream>>>(m, out);
}